// Round 6
// baseline (363.097 us; speedup 1.0000x reference)
//
#include <hip/hip_runtime.h>
#include <cstdint>

typedef unsigned short UST;
typedef __bf16 v8bf __attribute__((ext_vector_type(8)));
typedef float v4f __attribute__((ext_vector_type(4)));

static __device__ __forceinline__ UST f2b(float f) {
  union { float f; uint32_t u; } c; c.f = f;
  uint32_t u = c.u;
  u += 0x7fffu + ((u >> 16) & 1u);   // RNE
  return (UST)(u >> 16);
}
static __device__ __forceinline__ float b2f(UST h) {
  union { uint32_t u; float f; } c; c.u = ((uint32_t)h) << 16;
  return c.f;
}
static __device__ __forceinline__ uint32_t cvtpk(float lo, float hi) {
  uint32_t r;
  asm("v_cvt_pk_bf16_f32 %0, %1, %2" : "=v"(r) : "v"(lo), "v"(hi));
  return r;
}
static __device__ __forceinline__ float fexp2(float x) {  // 2^x
  float r;
  asm("v_exp_f32 %0, %1" : "=v"(r) : "v"(x));
  return r;
}
template <int N>
static __device__ __forceinline__ void wait_vm() {
  asm volatile("s_waitcnt vmcnt(%0)" :: "i"(N));
}

// async global->LDS, 16B per lane; global src per-lane, LDS dst wave-uniform+lane*16
static __device__ __forceinline__ void gl_lds16(const UST* g, UST* l) {
  __builtin_amdgcn_global_load_lds(
      (const __attribute__((address_space(1))) void*)g,
      (__attribute__((address_space(3))) void*)l, 16, 0, 0);
}

// ---------------- cast x f32 -> bf16, 8 elems/thread ----------------
__global__ __launch_bounds__(256) void k_cast(const float* __restrict__ src,
                                              UST* __restrict__ dst) {
  size_t i = (size_t)blockIdx.x * 256 + threadIdx.x;
  const float4* s4 = reinterpret_cast<const float4*>(src) + 2 * i;
  float4 a = s4[0], b = s4[1];
  union { UST s[8]; uint4 v; } r;
  r.s[0] = f2b(a.x); r.s[1] = f2b(a.y); r.s[2] = f2b(a.z); r.s[3] = f2b(a.w);
  r.s[4] = f2b(b.x); r.s[5] = f2b(b.y); r.s[6] = f2b(b.z); r.s[7] = f2b(b.w);
  reinterpret_cast<uint4*>(dst)[i] = r.v;
}

// ------------- transpose+cast: W [K][N] f32 -> dst [N][K] bf16 -------------
__global__ __launch_bounds__(256) void k_castT(const float* __restrict__ W,
                                               UST* __restrict__ dst, int N, int K) {
  __shared__ float tile[32][33];
  int nt = blockIdx.x * 32, kt = blockIdx.y * 32;
  int tx = threadIdx.x, ty = threadIdx.y;  // 32 x 8
#pragma unroll
  for (int r = 0; r < 4; ++r)
    tile[ty + r * 8][tx] = W[(size_t)(kt + ty + r * 8) * N + nt + tx];
  __syncthreads();
#pragma unroll
  for (int r = 0; r < 4; ++r)
    dst[(size_t)(nt + ty + r * 8) * K + kt + tx] = f2b(tile[tx][ty + r * 8]);
}

// ============ 8-phase counted-vmcnt GEMM: C[M][N] = A[M][K] * Bt[N][K]^T ============
template <int BM, int BN, int WM, int WN, int NMH, int EPI>
__global__ __launch_bounds__(512, 2) void k_gemm2(const UST* __restrict__ A,
                                                  const UST* __restrict__ Bt,
                                                  void* __restrict__ Cv,
                                                  const float* __restrict__ bias,
                                                  int M, int N, int K, int ntn) {
  constexpr int WMR = BM / WM, WNR = BN / WN;
  constexpr int MF = WMR / 16, NF = WNR / 16, MH = MF / NMH;
  constexpr int CA = BM / 128;            // full 8KB A-calls per s-half
  constexpr int CBF = BN / 128;           // full B-calls per s-half
  constexpr int BREM = (BN % 128) / 64;   // extra 64-row call (waves 0-3)
  constexpr int AELEMS = 4 * BM * 32;     // 2buf x 2s x BM x 32
  __shared__ __align__(16) UST lds[AELEMS + 4 * BN * 32];

  int tid = threadIdx.x, w = tid >> 6, lane = tid & 63;
  int lr = lane & 15, lg = lane >> 4;
  int wm = w / WN, wn = w % WN;

  // bijective XCD swizzle (grid % 8 == 0)
  int q = (int)gridDim.x >> 3;
  int bid = (int)blockIdx.x;
  int swz = (bid & 7) * q + (bid >> 3);
  int mBlk = (swz / ntn) * BM, nBlk = (swz % ntn) * BN;

  v4f acc[MF][NF];
#pragma unroll
  for (int i = 0; i < MF; ++i)
#pragma unroll
    for (int j = 0; j < NF; ++j) acc[i][j] = (v4f){0.f, 0.f, 0.f, 0.f};

  int srow = tid >> 2, scol = (tid & 3) * 8;
  const UST* Abase = A + (size_t)(mBlk + srow) * K + scol;
  const UST* Bbase = Bt + (size_t)(nBlk + srow) * K + scol;
  int ldsW = w * 512;  // wave-uniform chunk base (elems)

  auto stageA = [&](int buf, int s, int kt) {
#pragma unroll
    for (int i = 0; i < CA; ++i)
      gl_lds16(Abase + (size_t)(i * 128) * K + kt * 64 + s * 32,
               &lds[(buf * 2 + s) * BM * 32 + i * 4096 + ldsW]);
  };
  auto stageB = [&](int buf, int s, int kt) {
#pragma unroll
    for (int i = 0; i < CBF; ++i)
      gl_lds16(Bbase + (size_t)(i * 128) * K + kt * 64 + s * 32,
               &lds[AELEMS + (buf * 2 + s) * BN * 32 + i * 4096 + ldsW]);
    if constexpr (BREM) {
      if (w < 4)
        gl_lds16(Bbase + (size_t)(CBF * 128) * K + kt * 64 + s * 32,
                 &lds[AELEMS + (buf * 2 + s) * BN * 32 + CBF * 4096 + ldsW]);
    }
  };
  auto waitNK = [&]() {
    if constexpr (BREM) {
      if (w < 4) wait_vm<CA + CBF + 1>();
      else       wait_vm<CA + CBF>();
    } else {
      wait_vm<CA + CBF>();
    }
  };
  auto ldA = [&](int buf, int s, int f) -> v8bf {
    int row = wm * WMR + f * 16 + lr;
    return *(const v8bf*)&lds[((buf * 2 + s) * BM + row) * 32 + lg * 8];
  };
  auto ldB = [&](int buf, int s, int nf) -> v8bf {
    int row = wn * WNR + nf * 16 + lr;
    return *(const v8bf*)&lds[AELEMS + ((buf * 2 + s) * BN + row) * 32 + lg * 8];
  };

  int NT = K >> 6;  // K-tiles of 64
  stageA(0, 0, 0); stageB(0, 0, 0); stageA(0, 1, 0); stageB(0, 1, 0);
  waitNK();
  __builtin_amdgcn_s_barrier();

  for (int kt = 0; kt < NT; ++kt) {
    int buf = kt & 1, nb = buf ^ 1;
    bool more = (kt + 1 < NT);
#pragma unroll
    for (int s = 0; s < 2; ++s) {
      v8bf bfr[NF];
#pragma unroll
      for (int mh = 0; mh < NMH; ++mh) {
        v8bf afr[MH];
        if (mh == 0) {
#pragma unroll
          for (int nf = 0; nf < NF; ++nf) bfr[nf] = ldB(buf, s, nf);
        }
#pragma unroll
        for (int f = 0; f < MH; ++f) afr[f] = ldA(buf, s, mh * MH + f);
        if constexpr (NMH == 2) {
          if (mh == 0) {
            if (more) stageA(nb, s, kt + 1);
          } else {
            if (more) { stageB(nb, s, kt + 1); waitNK(); }
            else if (s == 0) wait_vm<0>();
          }
        } else {
          if (more) { stageA(nb, s, kt + 1); stageB(nb, s, kt + 1); waitNK(); }
          else if (s == 0) wait_vm<0>();
        }
        __builtin_amdgcn_s_barrier();
        __builtin_amdgcn_s_setprio(1);
#pragma unroll
        for (int f = 0; f < MH; ++f)
#pragma unroll
          for (int nf = 0; nf < NF; ++nf)
            acc[mh * MH + f][nf] = __builtin_amdgcn_mfma_f32_16x16x32_bf16(
                afr[f], bfr[nf], acc[mh * MH + f][nf], 0, 0, 0);
        __builtin_amdgcn_s_setprio(0);
        __builtin_amdgcn_s_barrier();
      }
    }
  }

  int row0 = mBlk + wm * WMR + lg * 4;
  int col0 = nBlk + wn * WNR + lr;
#pragma unroll
  for (int fm = 0; fm < MF; ++fm)
#pragma unroll
    for (int nf = 0; nf < NF; ++nf)
#pragma unroll
      for (int r = 0; r < 4; ++r) {
        int row = row0 + fm * 16 + r;
        int col = col0 + nf * 16;
        if constexpr (EPI == 0) {
          ((UST*)Cv)[(size_t)row * N + col] = f2b(acc[fm][nf][r]);
        } else {
          ((float*)Cv)[(size_t)row * N + col] = acc[fm][nf][r] + bias[col];
        }
      }
}

// ---------------- RoPE on q,k (q pre-scaled by 1/sqrt(64)) ----------------
__global__ __launch_bounds__(256) void k_rope(const UST* __restrict__ qkv,
                                              const float* __restrict__ cosT,
                                              const float* __restrict__ sinT,
                                              UST* __restrict__ qh,
                                              UST* __restrict__ kh) {
  int idx = blockIdx.x * 256 + threadIdx.x;
  int d = idx & 31;
  int hh = (idx >> 5) % 40;
  int row = idx / 1280;
  int l = row & 2047, b = row >> 11;
  int col = (hh < 32) ? hh * 64 : 2048 + (hh - 32) * 64;
  float t1 = b2f(qkv[(size_t)row * 3072 + col + d]);
  float t2 = b2f(qkv[(size_t)row * 3072 + col + d + 32]);
  float c = cosT[l * 64 + d], s = sinT[l * 64 + d];
  float o1 = t1 * c - t2 * s;
  float o2 = t2 * c + t1 * s;
  if (hh < 32) {
    size_t base = (((size_t)b * 32 + hh) * 2048 + l) * 64 + d;
    qh[base] = f2b(o1 * 0.125f);
    qh[base + 32] = f2b(o2 * 0.125f);
  } else {
    size_t base = (((size_t)b * 8 + (hh - 32)) * 2048 + l) * 64 + d;
    kh[base] = f2b(o1);
    kh[base + 32] = f2b(o2);
  }
}

// ---------------- V transpose: qkv v-slice -> vt [B][8][64][L] ----------------
__global__ __launch_bounds__(256) void k_vtrans(const UST* __restrict__ qkv,
                                                UST* __restrict__ vt) {
  __shared__ __align__(16) UST tl[64][72];
  int lt = blockIdx.x, bg = blockIdx.y;
  int b = bg >> 3, g = bg & 7;
  int t = threadIdx.x;
  int li = t >> 2, d0 = (t & 3) * 16;
  const UST* src = qkv + (size_t)(b * 2048 + lt * 64 + li) * 3072 + 2560 + g * 64 + d0;
  *(uint4*)&tl[li][d0] = *(const uint4*)src;
  *(uint4*)&tl[li][d0 + 8] = *(const uint4*)(src + 8);
  __syncthreads();
  int d = t >> 2, l0 = (t & 3) * 16;
  union { UST u[8]; uint4 v; } r0, r1;
#pragma unroll
  for (int e = 0; e < 8; ++e) r0.u[e] = tl[l0 + e][d];
#pragma unroll
  for (int e = 0; e < 8; ++e) r1.u[e] = tl[l0 + 8 + e][d];
  UST* dstp = vt + (size_t)((b * 8 + g) * 64 + d) * 2048 + (size_t)lt * 64 + l0;
  *(uint4*)dstp = r0.v;
  *(uint4*)(dstp + 8) = r1.v;
}

// ---------------- causal flash attention v3 ----------------
// grid (16, 32, 2) = 1024 blocks, qt = 15 - bx (long blocks dispatch first).
// 8 waves x 16 q-rows, KVBLK = 128. LDS 48KB -> 3 blocks/CU (24 waves).
// XOR swizzle on 16B slots: slot ^= (row&7); same involution on write AND read.
// p_s: one reused [16][64] buffer per wave; PV in two 64-kpos chunks
// (wave-private; DS pipe in-order, no barrier needed).
__global__ __launch_bounds__(512, 6) void k_attn(const UST* __restrict__ qh,
                                                 const UST* __restrict__ kh,
                                                 const UST* __restrict__ vt,
                                                 UST* __restrict__ outp) {
  __shared__ __align__(16) UST k_s[128 * 64];     // K tile [kpos][64], swizzled
  __shared__ __align__(16) UST v_s[64 * 128];     // V^T tile [d][128], swizzled
  __shared__ __align__(16) UST p_s[8 * 16 * 64];  // per-wave P chunk [16 q][64 k]
  int qt = 15 - (int)blockIdx.x;
  int h = blockIdx.y, b = blockIdx.z;
  int g = h >> 2;
  int tid = threadIdx.x, w = tid >> 6, lane = tid & 63;
  int lr = lane & 15, lg = lane >> 4;
  int lsw = (lr & 7) << 3;     // read-side swizzle (row == lr for all frag reads)
  int qbase = qt * 128 + w * 16;

  const UST* qp = qh + ((size_t)(b * 32 + h) * 2048 + qbase + lr) * 64 + lg * 8;
  v8bf qf0 = *(const v8bf*)qp;
  v8bf qf1 = *(const v8bf*)(qp + 32);

  float m = -1e30f, ls = 0.f;
  v4f o[4];
#pragma unroll
  for (int dt = 0; dt < 4; ++dt) o[dt] = (v4f){0.f, 0.f, 0.f, 0.f};

  int ksr = tid >> 2, ksc = (tid & 3) * 16;
  int vsr = tid >> 3, vsc = (tid & 7) * 16;
  const UST* kbase = kh + ((size_t)(b * 8 + g) * 2048 + ksr) * 64 + ksc;
  const UST* vbase = vt + ((size_t)(b * 8 + g) * 64 + vsr) * 2048 + vsc;
  int ksz = (ksr & 7) << 3, vsz = (vsr & 7) << 3;
  UST* kd0 = &k_s[ksr * 64 + (ksc ^ ksz)];
  UST* kd1 = &k_s[ksr * 64 + ((ksc + 8) ^ ksz)];
  UST* vd0 = &v_s[vsr * 128 + (vsc ^ vsz)];
  UST* vd1 = &v_s[vsr * 128 + ((vsc + 8) ^ vsz)];

  {  // stage tile 0
    uint4 a0 = *(const uint4*)kbase, a1 = *(const uint4*)(kbase + 8);
    uint4 b0 = *(const uint4*)vbase, b1 = *(const uint4*)(vbase + 8);
    *(uint4*)kd0 = a0; *(uint4*)kd1 = a1;
    *(uint4*)vd0 = b0; *(uint4*)vd1 = b1;
  }

  UST* pwb = &p_s[w * 1024 + lr * 64];

  for (int j = 0; j <= qt; ++j) {
    __syncthreads();  // staged tile visible
    bool pref = (j < qt);
    uint4 pk0, pk1, pv0, pv1;
    if (pref) {  // K register-prefetch early (V later, to bound VGPR pressure)
      const UST* kg = kbase + (size_t)(j + 1) * 8192;
      pk0 = *(const uint4*)kg; pk1 = *(const uint4*)(kg + 8);
    }

    // S^T = K * Q^T : 16 MFMAs; lane holds q-row lr, kpos = kt*16 + 4*lg + r
    v4f st[8];
    __builtin_amdgcn_s_setprio(1);
#pragma unroll
    for (int kt = 0; kt < 8; ++kt) {
      const UST* krow = &k_s[(kt * 16 + lr) * 64];
      v8bf kf0 = *(const v8bf*)&krow[(lg * 8) ^ lsw];
      v8bf kf1 = *(const v8bf*)&krow[(32 + lg * 8) ^ lsw];
      v4f z = (v4f){0.f, 0.f, 0.f, 0.f};
      z = __builtin_amdgcn_mfma_f32_16x16x32_bf16(kf0, qf0, z, 0, 0, 0);
      z = __builtin_amdgcn_mfma_f32_16x16x32_bf16(kf1, qf1, z, 0, 0, 0);
      st[kt] = z;
    }
    __builtin_amdgcn_s_setprio(0);
    if (j == qt) {  // diagonal: causal mask
      int qg = qbase + lr;
#pragma unroll
      for (int kt = 0; kt < 8; ++kt)
#pragma unroll
        for (int r = 0; r < 4; ++r) {
          int kp = j * 128 + kt * 16 + 4 * lg + r;
          if (kp > qg) st[kt][r] = -1e30f;
        }
    }

    // row max (row = lr, spread over 4 lg lanes)
    float t0 = fmaxf(fmaxf(st[0][0], st[0][1]), fmaxf(st[0][2], st[0][3]));
    float t1 = fmaxf(fmaxf(st[1][0], st[1][1]), fmaxf(st[1][2], st[1][3]));
    float t2 = fmaxf(fmaxf(st[2][0], st[2][1]), fmaxf(st[2][2], st[2][3]));
    float t3 = fmaxf(fmaxf(st[3][0], st[3][1]), fmaxf(st[3][2], st[3][3]));
    float t4 = fmaxf(fmaxf(st[4][0], st[4][1]), fmaxf(st[4][2], st[4][3]));
    float t5 = fmaxf(fmaxf(st[5][0], st[5][1]), fmaxf(st[5][2], st[5][3]));
    float t6 = fmaxf(fmaxf(st[6][0], st[6][1]), fmaxf(st[6][2], st[6][3]));
    float t7 = fmaxf(fmaxf(st[7][0], st[7][1]), fmaxf(st[7][2], st[7][3]));
    float mx = fmaxf(fmaxf(fmaxf(t0, t1), fmaxf(t2, t3)),
                     fmaxf(fmaxf(t4, t5), fmaxf(t6, t7)));
    mx = fmaxf(mx, __shfl_xor(mx, 16));
    mx = fmaxf(mx, __shfl_xor(mx, 32));

    if (!__all(mx <= m + 8.f)) {   // defer-max (T13)
      float mn = fmaxf(m, mx);
      float al = __expf(m - mn);
      m = mn;
      ls *= al;
#pragma unroll
      for (int r = 0; r < 4; ++r) {
        float ar = __shfl(al, 4 * lg + r);
        o[0][r] *= ar; o[1][r] *= ar; o[2][r] *= ar; o[3][r] *= ar;
      }
    }

    constexpr float LOG2E = 1.44269504f;
    float mlog = m * LOG2E;
    float rs = 0.f;
    // exp + P->LDS->PV in two 64-kpos chunks through the reused per-wave buffer
#pragma unroll
    for (int c = 0; c < 2; ++c) {
#pragma unroll
      for (int k2 = 0; k2 < 4; ++k2) {
        int kt = c * 4 + k2;
        float p0 = fexp2(__builtin_fmaf(st[kt][0], LOG2E, -mlog));
        float p1 = fexp2(__builtin_fmaf(st[kt][1], LOG2E, -mlog));
        float p2 = fexp2(__builtin_fmaf(st[kt][2], LOG2E, -mlog));
        float p3 = fexp2(__builtin_fmaf(st[kt][3], LOG2E, -mlog));
        rs += (p0 + p1) + (p2 + p3);
        uint2 q2;
        q2.x = cvtpk(p0, p1);
        q2.y = cvtpk(p2, p3);
        // elem = 16*k2 + 4*lg -> swizzle 16B-slot part, keep 8B half
        *(uint2*)&pwb[((k2 * 16 + (lg >> 1) * 8) ^ lsw) + (lg & 1) * 4] = q2;
      }
      if (c == 0 && pref) {  // V register-prefetch hides under PV compute
        const UST* vg = vbase + (j + 1) * 128;
        pv0 = *(const uint4*)vg; pv1 = *(const uint4*)(vg + 8);
      }
      __builtin_amdgcn_s_setprio(1);
#pragma unroll
      for (int kkl = 0; kkl < 2; ++kkl) {
        int kk = c * 2 + kkl;
        v8bf pa = *(const v8bf*)&pwb[(kkl * 32 + lg * 8) ^ lsw];
#pragma unroll
        for (int dt = 0; dt < 4; ++dt) {
          v8bf vb = *(const v8bf*)&v_s[(dt * 16 + lr) * 128 + ((kk * 32 + lg * 8) ^ lsw)];
          o[dt] = __builtin_amdgcn_mfma_f32_16x16x32_bf16(pa, vb, o[dt], 0, 0, 0);
        }
      }
      __builtin_amdgcn_s_setprio(0);
    }
    rs += __shfl_xor(rs, 16);
    rs += __shfl_xor(rs, 32);
    ls += rs;

    __syncthreads();  // tile reads done
    if (pref) {
      *(uint4*)kd0 = pk0; *(uint4*)kd1 = pk1;
      *(uint4*)vd0 = pv0; *(uint4*)vd1 = pv1;
    }
  }

  // epilogue: normalize and store O as [B*L][H*64] bf16
  float iv = 1.f / ls;
#pragma unroll
  for (int r = 0; r < 4; ++r) {
    float ivr = __shfl(iv, 4 * lg + r);
    size_t rowb = ((size_t)b * 2048 + qbase + 4 * lg + r) * 2048 + h * 64 + lr;
#pragma unroll
    for (int dt = 0; dt < 4; ++dt)
      outp[rowb + dt * 16] = f2b(o[dt][r] * ivr);
  }
}

// ---------------- launch ----------------
extern "C" void kernel_launch(void* const* d_in, const int* in_sizes, int n_in,
                              void* d_out, int out_size, void* d_ws, size_t ws_size,
                              hipStream_t stream) {
  const float* x    = (const float*)d_in[0];
  const float* cosT = (const float*)d_in[2];
  const float* sinT = (const float*)d_in[3];
  const float* Wq   = (const float*)d_in[4];
  const float* Wk   = (const float*)d_in[5];
  const float* Wv   = (const float*)d_in[6];
  const float* Wo   = (const float*)d_in[7];
  const float* bo   = (const float*)d_in[8];
  float* out = (float*)d_out;

  char* ws = (char*)d_ws;
  UST* xb   = (UST*)(ws);                       // 16777216 B
  UST* wcat = (UST*)(ws + 16777216);            // 12582912 B
  UST* wot  = (UST*)(ws + 29360128);            //  8388608 B
  UST* qkv  = (UST*)(ws + 37748736);            // 25165824 B
  UST* qhp  = (UST*)(ws + 62914560);            // 16777216 B
  UST* khp  = (UST*)(ws + 79691776);            //  4194304 B
  UST* vtp  = (UST*)(ws + 83886080);            //  4194304 B
  UST* attn_o = xb;  // xb dead after QKV GEMM

  k_cast<<<4096, 256, 0, stream>>>(x, xb);
  k_castT<<<dim3(64, 64), dim3(32, 8), 0, stream>>>(Wq, wcat, 2048, 2048);
  k_castT<<<dim3(16, 64), dim3(32, 8), 0, stream>>>(Wk, wcat + (size_t)2048 * 2048, 512, 2048);
  k_castT<<<dim3(16, 64), dim3(32, 8), 0, stream>>>(Wv, wcat + (size_t)2560 * 2048, 512, 2048);
  k_castT<<<dim3(64, 64), dim3(32, 8), 0, stream>>>(Wo, wot, 2048, 2048);

  // QKV: M=4096, N=3072, K=2048; 256x192 tiles -> 16x16 = 256 blocks (perfect fill)
  k_gemm2<256, 192, 2, 4, 2, 0><<<256, 512, 0, stream>>>(xb, wcat, qkv, nullptr,
                                                         4096, 3072, 2048, 16);
  k_rope<<<20480, 256, 0, stream>>>(qkv, cosT, sinT, qhp, khp);
  k_vtrans<<<dim3(32, 16), 256, 0, stream>>>(qkv, vtp);
  k_attn<<<dim3(16, 32, 2), 512, 0, stream>>>(qhp, khp, vtp, attn_o);
  // out: M=4096, N=2048, K=2048; 256x128 tiles -> 16x16 = 256 blocks (full fill)
  k_gemm2<256, 128, 4, 2, 1, 1><<<256, 512, 0, stream>>>(attn_o, wot, out, bo,
                                                         4096, 2048, 2048, 16);
}

// Round 7
// 237.502 us; speedup vs baseline: 1.5288x; 1.5288x over previous
//
#include <hip/hip_runtime.h>
#include <cstdint>

typedef unsigned short UST;
typedef __bf16 v8bf __attribute__((ext_vector_type(8)));
typedef float v4f __attribute__((ext_vector_type(4)));

static __device__ __forceinline__ UST f2b(float f) {
  union { float f; uint32_t u; } c; c.f = f;
  uint32_t u = c.u;
  u += 0x7fffu + ((u >> 16) & 1u);   // RNE
  return (UST)(u >> 16);
}
static __device__ __forceinline__ float b2f(UST h) {
  union { uint32_t u; float f; } c; c.u = ((uint32_t)h) << 16;
  return c.f;
}
static __device__ __forceinline__ uint32_t cvtpk(float lo, float hi) {
  uint32_t r;
  asm("v_cvt_pk_bf16_f32 %0, %1, %2" : "=v"(r) : "v"(lo), "v"(hi));
  return r;
}
static __device__ __forceinline__ float fexp2(float x) {  // 2^x
  float r;
  asm("v_exp_f32 %0, %1" : "=v"(r) : "v"(x));
  return r;
}
template <int N>
static __device__ __forceinline__ void wait_vm() {
  asm volatile("s_waitcnt vmcnt(%0)" :: "i"(N));
}

// async global->LDS, 16B per lane; global src per-lane, LDS dst wave-uniform+lane*16
static __device__ __forceinline__ void gl_lds16(const UST* g, UST* l) {
  __builtin_amdgcn_global_load_lds(
      (const __attribute__((address_space(1))) void*)g,
      (__attribute__((address_space(3))) void*)l, 16, 0, 0);
}

// ---------------- cast x f32 -> bf16, 8 elems/thread ----------------
__global__ __launch_bounds__(256) void k_cast(const float* __restrict__ src,
                                              UST* __restrict__ dst) {
  size_t i = (size_t)blockIdx.x * 256 + threadIdx.x;
  const float4* s4 = reinterpret_cast<const float4*>(src) + 2 * i;
  float4 a = s4[0], b = s4[1];
  union { UST s[8]; uint4 v; } r;
  r.s[0] = f2b(a.x); r.s[1] = f2b(a.y); r.s[2] = f2b(a.z); r.s[3] = f2b(a.w);
  r.s[4] = f2b(b.x); r.s[5] = f2b(b.y); r.s[6] = f2b(b.z); r.s[7] = f2b(b.w);
  reinterpret_cast<uint4*>(dst)[i] = r.v;
}

// ------------- transpose+cast: W [K][N] f32 -> dst [N][K] bf16 -------------
__global__ __launch_bounds__(256) void k_castT(const float* __restrict__ W,
                                               UST* __restrict__ dst, int N, int K) {
  __shared__ float tile[32][33];
  int nt = blockIdx.x * 32, kt = blockIdx.y * 32;
  int tx = threadIdx.x, ty = threadIdx.y;  // 32 x 8
#pragma unroll
  for (int r = 0; r < 4; ++r)
    tile[ty + r * 8][tx] = W[(size_t)(kt + ty + r * 8) * N + nt + tx];
  __syncthreads();
#pragma unroll
  for (int r = 0; r < 4; ++r)
    dst[(size_t)(nt + ty + r * 8) * K + kt + tx] = f2b(tile[tx][ty + r * 8]);
}

// ============ 8-phase counted-vmcnt GEMM: C[M][N] = A[M][K] * Bt[N][K]^T ============
template <int BM, int BN, int WM, int WN, int NMH, int EPI>
__global__ __launch_bounds__(512, 2) void k_gemm2(const UST* __restrict__ A,
                                                  const UST* __restrict__ Bt,
                                                  void* __restrict__ Cv,
                                                  const float* __restrict__ bias,
                                                  int M, int N, int K, int ntn) {
  constexpr int WMR = BM / WM, WNR = BN / WN;
  constexpr int MF = WMR / 16, NF = WNR / 16, MH = MF / NMH;
  constexpr int CA = BM / 128;            // full 8KB A-calls per s-half
  constexpr int CBF = BN / 128;           // full B-calls per s-half
  constexpr int BREM = (BN % 128) / 64;   // extra 64-row call (waves 0-3)
  constexpr int AELEMS = 4 * BM * 32;     // 2buf x 2s x BM x 32
  __shared__ __align__(16) UST lds[AELEMS + 4 * BN * 32];

  int tid = threadIdx.x, w = tid >> 6, lane = tid & 63;
  int lr = lane & 15, lg = lane >> 4;
  int wm = w / WN, wn = w % WN;

  // bijective XCD swizzle (grid % 8 == 0)
  int q = (int)gridDim.x >> 3;
  int bid = (int)blockIdx.x;
  int swz = (bid & 7) * q + (bid >> 3);
  int mBlk = (swz / ntn) * BM, nBlk = (swz % ntn) * BN;

  v4f acc[MF][NF];
#pragma unroll
  for (int i = 0; i < MF; ++i)
#pragma unroll
    for (int j = 0; j < NF; ++j) acc[i][j] = (v4f){0.f, 0.f, 0.f, 0.f};

  int srow = tid >> 2, scol = (tid & 3) * 8;
  const UST* Abase = A + (size_t)(mBlk + srow) * K + scol;
  const UST* Bbase = Bt + (size_t)(nBlk + srow) * K + scol;
  int ldsW = w * 512;  // wave-uniform chunk base (elems)

  auto stageA = [&](int buf, int s, int kt) {
#pragma unroll
    for (int i = 0; i < CA; ++i)
      gl_lds16(Abase + (size_t)(i * 128) * K + kt * 64 + s * 32,
               &lds[(buf * 2 + s) * BM * 32 + i * 4096 + ldsW]);
  };
  auto stageB = [&](int buf, int s, int kt) {
#pragma unroll
    for (int i = 0; i < CBF; ++i)
      gl_lds16(Bbase + (size_t)(i * 128) * K + kt * 64 + s * 32,
               &lds[AELEMS + (buf * 2 + s) * BN * 32 + i * 4096 + ldsW]);
    if constexpr (BREM) {
      if (w < 4)
        gl_lds16(Bbase + (size_t)(CBF * 128) * K + kt * 64 + s * 32,
                 &lds[AELEMS + (buf * 2 + s) * BN * 32 + CBF * 4096 + ldsW]);
    }
  };
  auto waitNK = [&]() {
    if constexpr (BREM) {
      if (w < 4) wait_vm<CA + CBF + 1>();
      else       wait_vm<CA + CBF>();
    } else {
      wait_vm<CA + CBF>();
    }
  };
  auto ldA = [&](int buf, int s, int f) -> v8bf {
    int row = wm * WMR + f * 16 + lr;
    return *(const v8bf*)&lds[((buf * 2 + s) * BM + row) * 32 + lg * 8];
  };
  auto ldB = [&](int buf, int s, int nf) -> v8bf {
    int row = wn * WNR + nf * 16 + lr;
    return *(const v8bf*)&lds[AELEMS + ((buf * 2 + s) * BN + row) * 32 + lg * 8];
  };

  int NT = K >> 6;  // K-tiles of 64
  stageA(0, 0, 0); stageB(0, 0, 0); stageA(0, 1, 0); stageB(0, 1, 0);
  waitNK();
  __builtin_amdgcn_s_barrier();

  for (int kt = 0; kt < NT; ++kt) {
    int buf = kt & 1, nb = buf ^ 1;
    bool more = (kt + 1 < NT);
#pragma unroll
    for (int s = 0; s < 2; ++s) {
      v8bf bfr[NF];
#pragma unroll
      for (int mh = 0; mh < NMH; ++mh) {
        v8bf afr[MH];
        if (mh == 0) {
#pragma unroll
          for (int nf = 0; nf < NF; ++nf) bfr[nf] = ldB(buf, s, nf);
        }
#pragma unroll
        for (int f = 0; f < MH; ++f) afr[f] = ldA(buf, s, mh * MH + f);
        if constexpr (NMH == 2) {
          if (mh == 0) {
            if (more) stageA(nb, s, kt + 1);
          } else {
            if (more) { stageB(nb, s, kt + 1); waitNK(); }
            else if (s == 0) wait_vm<0>();
          }
        } else {
          if (more) { stageA(nb, s, kt + 1); stageB(nb, s, kt + 1); waitNK(); }
          else if (s == 0) wait_vm<0>();
        }
        __builtin_amdgcn_s_barrier();
        __builtin_amdgcn_s_setprio(1);
#pragma unroll
        for (int f = 0; f < MH; ++f)
#pragma unroll
          for (int nf = 0; nf < NF; ++nf)
            acc[mh * MH + f][nf] = __builtin_amdgcn_mfma_f32_16x16x32_bf16(
                afr[f], bfr[nf], acc[mh * MH + f][nf], 0, 0, 0);
        __builtin_amdgcn_s_setprio(0);
        __builtin_amdgcn_s_barrier();
      }
    }
  }

  int row0 = mBlk + wm * WMR + lg * 4;
  int col0 = nBlk + wn * WNR + lr;
#pragma unroll
  for (int fm = 0; fm < MF; ++fm)
#pragma unroll
    for (int nf = 0; nf < NF; ++nf)
#pragma unroll
      for (int r = 0; r < 4; ++r) {
        int row = row0 + fm * 16 + r;
        int col = col0 + nf * 16;
        if constexpr (EPI == 0) {
          ((UST*)Cv)[(size_t)row * N + col] = f2b(acc[fm][nf][r]);
        } else {
          ((float*)Cv)[(size_t)row * N + col] = acc[fm][nf][r] + bias[col];
        }
      }
}

// ---------------- RoPE on q,k (q pre-scaled by 1/sqrt(64)) ----------------
__global__ __launch_bounds__(256) void k_rope(const UST* __restrict__ qkv,
                                              const float* __restrict__ cosT,
                                              const float* __restrict__ sinT,
                                              UST* __restrict__ qh,
                                              UST* __restrict__ kh) {
  int idx = blockIdx.x * 256 + threadIdx.x;
  int d = idx & 31;
  int hh = (idx >> 5) % 40;
  int row = idx / 1280;
  int l = row & 2047, b = row >> 11;
  int col = (hh < 32) ? hh * 64 : 2048 + (hh - 32) * 64;
  float t1 = b2f(qkv[(size_t)row * 3072 + col + d]);
  float t2 = b2f(qkv[(size_t)row * 3072 + col + d + 32]);
  float c = cosT[l * 64 + d], s = sinT[l * 64 + d];
  float o1 = t1 * c - t2 * s;
  float o2 = t2 * c + t1 * s;
  if (hh < 32) {
    size_t base = (((size_t)b * 32 + hh) * 2048 + l) * 64 + d;
    qh[base] = f2b(o1 * 0.125f);
    qh[base + 32] = f2b(o2 * 0.125f);
  } else {
    size_t base = (((size_t)b * 8 + (hh - 32)) * 2048 + l) * 64 + d;
    kh[base] = f2b(o1);
    kh[base + 32] = f2b(o2);
  }
}

// ---------------- V transpose: qkv v-slice -> vt [B][8][64][L] ----------------
__global__ __launch_bounds__(256) void k_vtrans(const UST* __restrict__ qkv,
                                                UST* __restrict__ vt) {
  __shared__ __align__(16) UST tl[64][72];
  int lt = blockIdx.x, bg = blockIdx.y;
  int b = bg >> 3, g = bg & 7;
  int t = threadIdx.x;
  int li = t >> 2, d0 = (t & 3) * 16;
  const UST* src = qkv + (size_t)(b * 2048 + lt * 64 + li) * 3072 + 2560 + g * 64 + d0;
  *(uint4*)&tl[li][d0] = *(const uint4*)src;
  *(uint4*)&tl[li][d0 + 8] = *(const uint4*)(src + 8);
  __syncthreads();
  int d = t >> 2, l0 = (t & 3) * 16;
  union { UST u[8]; uint4 v; } r0, r1;
#pragma unroll
  for (int e = 0; e < 8; ++e) r0.u[e] = tl[l0 + e][d];
#pragma unroll
  for (int e = 0; e < 8; ++e) r1.u[e] = tl[l0 + 8 + e][d];
  UST* dstp = vt + (size_t)((b * 8 + g) * 64 + d) * 2048 + (size_t)lt * 64 + l0;
  *(uint4*)dstp = r0.v;
  *(uint4*)(dstp + 8) = r1.v;
}

// ---------------- causal flash attention v3 (spill-free build) ----------------
// grid (16, 32, 2) = 1024 blocks, qt = 15 - bx (long blocks dispatch first).
// 8 waves x 16 q-rows, KVBLK = 128. LDS 48KB; launch_bounds(512,4): VGPR cap 128
// (round-5 evidence: this body compiles ~64-80 VGPR, no spill). If actual VGPR
// <= 85, HW grants 3 blocks/CU (24 waves) via the 48KB LDS; else falls back to 2.
// XOR swizzle on 16B slots: slot ^= (row&7); same involution on write AND read.
__global__ __launch_bounds__(512, 4) void k_attn(const UST* __restrict__ qh,
                                                 const UST* __restrict__ kh,
                                                 const UST* __restrict__ vt,
                                                 UST* __restrict__ outp) {
  __shared__ __align__(16) UST k_s[128 * 64];     // K tile [kpos][64], swizzled
  __shared__ __align__(16) UST v_s[64 * 128];     // V^T tile [d][128], swizzled
  __shared__ __align__(16) UST p_s[8 * 16 * 64];  // per-wave P chunk [16 q][64 k]
  int qt = 15 - (int)blockIdx.x;
  int h = blockIdx.y, b = blockIdx.z;
  int g = h >> 2;
  int tid = threadIdx.x, w = tid >> 6, lane = tid & 63;
  int lr = lane & 15, lg = lane >> 4;
  int lsw = (lr & 7) << 3;     // read-side swizzle (row == lr for all frag reads)
  int qbase = qt * 128 + w * 16;

  const UST* qp = qh + ((size_t)(b * 32 + h) * 2048 + qbase + lr) * 64 + lg * 8;
  v8bf qf0 = *(const v8bf*)qp;
  v8bf qf1 = *(const v8bf*)(qp + 32);

  float m = -1e30f, ls = 0.f;
  v4f o[4];
#pragma unroll
  for (int dt = 0; dt < 4; ++dt) o[dt] = (v4f){0.f, 0.f, 0.f, 0.f};

  int ksr = tid >> 2, ksc = (tid & 3) * 16;
  int vsr = tid >> 3, vsc = (tid & 7) * 16;
  const UST* kbase = kh + ((size_t)(b * 8 + g) * 2048 + ksr) * 64 + ksc;
  const UST* vbase = vt + ((size_t)(b * 8 + g) * 64 + vsr) * 2048 + vsc;
  int ksz = (ksr & 7) << 3, vsz = (vsr & 7) << 3;
  UST* kd0 = &k_s[ksr * 64 + (ksc ^ ksz)];
  UST* kd1 = &k_s[ksr * 64 + ((ksc + 8) ^ ksz)];
  UST* vd0 = &v_s[vsr * 128 + (vsc ^ vsz)];
  UST* vd1 = &v_s[vsr * 128 + ((vsc + 8) ^ vsz)];

  {  // stage tile 0
    uint4 a0 = *(const uint4*)kbase, a1 = *(const uint4*)(kbase + 8);
    uint4 b0 = *(const uint4*)vbase, b1 = *(const uint4*)(vbase + 8);
    *(uint4*)kd0 = a0; *(uint4*)kd1 = a1;
    *(uint4*)vd0 = b0; *(uint4*)vd1 = b1;
  }

  UST* pwb = &p_s[w * 1024 + lr * 64];

  for (int j = 0; j <= qt; ++j) {
    __syncthreads();  // staged tile visible
    bool pref = (j < qt);
    uint4 pk0, pk1, pv0, pv1;
    if (pref) {  // K register-prefetch early (V later, to bound VGPR pressure)
      const UST* kg = kbase + (size_t)(j + 1) * 8192;
      pk0 = *(const uint4*)kg; pk1 = *(const uint4*)(kg + 8);
    }

    // S^T = K * Q^T : 16 MFMAs; lane holds q-row lr, kpos = kt*16 + 4*lg + r
    v4f st[8];
    __builtin_amdgcn_s_setprio(1);
#pragma unroll
    for (int kt = 0; kt < 8; ++kt) {
      const UST* krow = &k_s[(kt * 16 + lr) * 64];
      v8bf kf0 = *(const v8bf*)&krow[(lg * 8) ^ lsw];
      v8bf kf1 = *(const v8bf*)&krow[(32 + lg * 8) ^ lsw];
      v4f z = (v4f){0.f, 0.f, 0.f, 0.f};
      z = __builtin_amdgcn_mfma_f32_16x16x32_bf16(kf0, qf0, z, 0, 0, 0);
      z = __builtin_amdgcn_mfma_f32_16x16x32_bf16(kf1, qf1, z, 0, 0, 0);
      st[kt] = z;
    }
    __builtin_amdgcn_s_setprio(0);
    if (j == qt) {  // diagonal: causal mask
      int qg = qbase + lr;
#pragma unroll
      for (int kt = 0; kt < 8; ++kt)
#pragma unroll
        for (int r = 0; r < 4; ++r) {
          int kp = j * 128 + kt * 16 + 4 * lg + r;
          if (kp > qg) st[kt][r] = -1e30f;
        }
    }

    // row max (row = lr, spread over 4 lg lanes)
    float t0 = fmaxf(fmaxf(st[0][0], st[0][1]), fmaxf(st[0][2], st[0][3]));
    float t1 = fmaxf(fmaxf(st[1][0], st[1][1]), fmaxf(st[1][2], st[1][3]));
    float t2 = fmaxf(fmaxf(st[2][0], st[2][1]), fmaxf(st[2][2], st[2][3]));
    float t3 = fmaxf(fmaxf(st[3][0], st[3][1]), fmaxf(st[3][2], st[3][3]));
    float t4 = fmaxf(fmaxf(st[4][0], st[4][1]), fmaxf(st[4][2], st[4][3]));
    float t5 = fmaxf(fmaxf(st[5][0], st[5][1]), fmaxf(st[5][2], st[5][3]));
    float t6 = fmaxf(fmaxf(st[6][0], st[6][1]), fmaxf(st[6][2], st[6][3]));
    float t7 = fmaxf(fmaxf(st[7][0], st[7][1]), fmaxf(st[7][2], st[7][3]));
    float mx = fmaxf(fmaxf(fmaxf(t0, t1), fmaxf(t2, t3)),
                     fmaxf(fmaxf(t4, t5), fmaxf(t6, t7)));
    mx = fmaxf(mx, __shfl_xor(mx, 16));
    mx = fmaxf(mx, __shfl_xor(mx, 32));

    if (!__all(mx <= m + 8.f)) {   // defer-max (T13)
      float mn = fmaxf(m, mx);
      float al = __expf(m - mn);
      m = mn;
      ls *= al;
#pragma unroll
      for (int r = 0; r < 4; ++r) {
        float ar = __shfl(al, 4 * lg + r);
        o[0][r] *= ar; o[1][r] *= ar; o[2][r] *= ar; o[3][r] *= ar;
      }
    }

    constexpr float LOG2E = 1.44269504f;
    float mlog = m * LOG2E;
    float rs = 0.f;
    // exp + P->LDS->PV in two 64-kpos chunks through the reused per-wave buffer
#pragma unroll
    for (int c = 0; c < 2; ++c) {
#pragma unroll
      for (int k2 = 0; k2 < 4; ++k2) {
        int kt = c * 4 + k2;
        float p0 = fexp2(__builtin_fmaf(st[kt][0], LOG2E, -mlog));
        float p1 = fexp2(__builtin_fmaf(st[kt][1], LOG2E, -mlog));
        float p2 = fexp2(__builtin_fmaf(st[kt][2], LOG2E, -mlog));
        float p3 = fexp2(__builtin_fmaf(st[kt][3], LOG2E, -mlog));
        rs += (p0 + p1) + (p2 + p3);
        uint2 q2;
        q2.x = cvtpk(p0, p1);
        q2.y = cvtpk(p2, p3);
        // elem = 16*k2 + 4*lg -> swizzle 16B-slot part, keep 8B half
        *(uint2*)&pwb[((k2 * 16 + (lg >> 1) * 8) ^ lsw) + (lg & 1) * 4] = q2;
      }
      if (c == 0 && pref) {  // V register-prefetch hides under PV compute
        const UST* vg = vbase + (j + 1) * 128;
        pv0 = *(const uint4*)vg; pv1 = *(const uint4*)(vg + 8);
      }
      __builtin_amdgcn_s_setprio(1);
#pragma unroll
      for (int kkl = 0; kkl < 2; ++kkl) {
        int kk = c * 2 + kkl;
        v8bf pa = *(const v8bf*)&pwb[(kkl * 32 + lg * 8) ^ lsw];
#pragma unroll
        for (int dt = 0; dt < 4; ++dt) {
          v8bf vb = *(const v8bf*)&v_s[(dt * 16 + lr) * 128 + ((kk * 32 + lg * 8) ^ lsw)];
          o[dt] = __builtin_amdgcn_mfma_f32_16x16x32_bf16(pa, vb, o[dt], 0, 0, 0);
        }
      }
      __builtin_amdgcn_s_setprio(0);
    }
    rs += __shfl_xor(rs, 16);
    rs += __shfl_xor(rs, 32);
    ls += rs;

    __syncthreads();  // tile reads done
    if (pref) {
      *(uint4*)kd0 = pk0; *(uint4*)kd1 = pk1;
      *(uint4*)vd0 = pv0; *(uint4*)vd1 = pv1;
    }
  }

  // epilogue: normalize and store O as [B*L][H*64] bf16
  float iv = 1.f / ls;
#pragma unroll
  for (int r = 0; r < 4; ++r) {
    float ivr = __shfl(iv, 4 * lg + r);
    size_t rowb = ((size_t)b * 2048 + qbase + 4 * lg + r) * 2048 + h * 64 + lr;
#pragma unroll
    for (int dt = 0; dt < 4; ++dt)
      outp[rowb + dt * 16] = f2b(o[dt][r] * ivr);
  }
}

// ---------------- launch ----------------
extern "C" void kernel_launch(void* const* d_in, const int* in_sizes, int n_in,
                              void* d_out, int out_size, void* d_ws, size_t ws_size,
                              hipStream_t stream) {
  const float* x    = (const float*)d_in[0];
  const float* cosT = (const float*)d_in[2];
  const float* sinT = (const float*)d_in[3];
  const float* Wq   = (const float*)d_in[4];
  const float* Wk   = (const float*)d_in[5];
  const float* Wv   = (const float*)d_in[6];
  const float* Wo   = (const float*)d_in[7];
  const float* bo   = (const float*)d_in[8];
  float* out = (float*)d_out;

  char* ws = (char*)d_ws;
  UST* xb   = (UST*)(ws);                       // 16777216 B
  UST* wcat = (UST*)(ws + 16777216);            // 12582912 B
  UST* wot  = (UST*)(ws + 29360128);            //  8388608 B
  UST* qkv  = (UST*)(ws + 37748736);            // 25165824 B
  UST* qhp  = (UST*)(ws + 62914560);            // 16777216 B
  UST* khp  = (UST*)(ws + 79691776);            //  4194304 B
  UST* vtp  = (UST*)(ws + 83886080);            //  4194304 B
  UST* attn_o = xb;  // xb dead after QKV GEMM

  k_cast<<<4096, 256, 0, stream>>>(x, xb);
  k_castT<<<dim3(64, 64), dim3(32, 8), 0, stream>>>(Wq, wcat, 2048, 2048);
  k_castT<<<dim3(16, 64), dim3(32, 8), 0, stream>>>(Wk, wcat + (size_t)2048 * 2048, 512, 2048);
  k_castT<<<dim3(16, 64), dim3(32, 8), 0, stream>>>(Wv, wcat + (size_t)2560 * 2048, 512, 2048);
  k_castT<<<dim3(64, 64), dim3(32, 8), 0, stream>>>(Wo, wot, 2048, 2048);

  // QKV: M=4096, N=3072, K=2048; 256x192 tiles -> 16x16 = 256 blocks (perfect fill)
  k_gemm2<256, 192, 2, 4, 2, 0><<<256, 512, 0, stream>>>(xb, wcat, qkv, nullptr,
                                                         4096, 3072, 2048, 16);
  k_rope<<<20480, 256, 0, stream>>>(qkv, cosT, sinT, qhp, khp);
  k_vtrans<<<dim3(32, 16), 256, 0, stream>>>(qkv, vtp);
  k_attn<<<dim3(16, 32, 2), 512, 0, stream>>>(qhp, khp, vtp, attn_o);
  // out: M=4096, N=2048, K=2048; 256x128 tiles -> 16x16 = 256 blocks (full fill)
  k_gemm2<256, 128, 4, 2, 1, 1><<<256, 512, 0, stream>>>(attn_o, wot, out, bo,
                                                         4096, 2048, 2048, 16);
}

// Round 8
// 218.478 us; speedup vs baseline: 1.6619x; 1.0871x over previous
//
#include <hip/hip_runtime.h>
#include <cstdint>

typedef unsigned short UST;
typedef __bf16 v8bf __attribute__((ext_vector_type(8)));
typedef float v4f __attribute__((ext_vector_type(4)));

static __device__ __forceinline__ UST f2b(float f) {
  union { float f; uint32_t u; } c; c.f = f;
  uint32_t u = c.u;
  u += 0x7fffu + ((u >> 16) & 1u);   // RNE
  return (UST)(u >> 16);
}
static __device__ __forceinline__ float b2f(UST h) {
  union { uint32_t u; float f; } c; c.u = ((uint32_t)h) << 16;
  return c.f;
}
static __device__ __forceinline__ uint32_t cvtpk(float lo, float hi) {
  uint32_t r;
  asm("v_cvt_pk_bf16_f32 %0, %1, %2" : "=v"(r) : "v"(lo), "v"(hi));
  return r;
}
static __device__ __forceinline__ float fexp2(float x) {  // 2^x
  float r;
  asm("v_exp_f32 %0, %1" : "=v"(r) : "v"(x));
  return r;
}
template <int N>
static __device__ __forceinline__ void wait_vm() {
  asm volatile("s_waitcnt vmcnt(%0)" :: "i"(N));
}

// async global->LDS, 16B per lane; global src per-lane, LDS dst wave-uniform+lane*16
static __device__ __forceinline__ void gl_lds16(const UST* g, UST* l) {
  __builtin_amdgcn_global_load_lds(
      (const __attribute__((address_space(1))) void*)g,
      (__attribute__((address_space(3))) void*)l, 16, 0, 0);
}

// ---------------- cast x f32 -> bf16, 8 elems/thread ----------------
__global__ __launch_bounds__(256) void k_cast(const float* __restrict__ src,
                                              UST* __restrict__ dst) {
  size_t i = (size_t)blockIdx.x * 256 + threadIdx.x;
  const float4* s4 = reinterpret_cast<const float4*>(src) + 2 * i;
  float4 a = s4[0], b = s4[1];
  union { UST s[8]; uint4 v; } r;
  r.s[0] = f2b(a.x); r.s[1] = f2b(a.y); r.s[2] = f2b(a.z); r.s[3] = f2b(a.w);
  r.s[4] = f2b(b.x); r.s[5] = f2b(b.y); r.s[6] = f2b(b.z); r.s[7] = f2b(b.w);
  reinterpret_cast<uint4*>(dst)[i] = r.v;
}

// ------------- transpose+cast: W [K][N] f32 -> dst [N][K] bf16 -------------
__global__ __launch_bounds__(256) void k_castT(const float* __restrict__ W,
                                               UST* __restrict__ dst, int N, int K) {
  __shared__ float tile[32][33];
  int nt = blockIdx.x * 32, kt = blockIdx.y * 32;
  int tx = threadIdx.x, ty = threadIdx.y;  // 32 x 8
#pragma unroll
  for (int r = 0; r < 4; ++r)
    tile[ty + r * 8][tx] = W[(size_t)(kt + ty + r * 8) * N + nt + tx];
  __syncthreads();
#pragma unroll
  for (int r = 0; r < 4; ++r)
    dst[(size_t)(nt + ty + r * 8) * K + kt + tx] = f2b(tile[tx][ty + r * 8]);
}

// ====== double-buffered GEMM, 128B swizzled LDS rows: C[M][N] = A * Bt^T ======
// BK=64; LDS rows hold a full 64-k slice (128B = 8 x 16B slots), swizzled
// slot ^= (row&7) -- written via inverse-swizzled per-lane GLOBAL source with a
// linear gl_lds dest (both-sides rule), read with the same XOR. Frag reads are
// bank-uniform (8 lanes per 16B column = LDS floor). Stage call = 512 lanes x
// 16B = 64 rows, so CA=BM/64, CB=BN/64 (wave-uniform vmcnt, no remainder).
// Per K-tile: {issue CA+CB calls for kt+1 -> vmcnt(CA+CB) -> barrier ->
//   22 ds_read + 48 MFMA (no inner barriers) -> barrier}. vmcnt never 0 mid-loop.
template <int BM, int BN, int WM, int WN, int EPI>
__global__ __launch_bounds__(512, 2) void k_gemm2(const UST* __restrict__ A,
                                                  const UST* __restrict__ Bt,
                                                  void* __restrict__ Cv,
                                                  const float* __restrict__ bias,
                                                  int M, int N, int K, int ntn) {
  constexpr int WMR = BM / WM, WNR = BN / WN;
  constexpr int MF = WMR / 16, NF = WNR / 16;
  constexpr int CA = BM / 64, CB = BN / 64;   // gl_lds call-sets per tile
  constexpr int NKEEP = CA + CB;
  constexpr int AE = 2 * BM * 64;             // A region elems (2 buffers)
  __shared__ __align__(16) UST lds[AE + 2 * BN * 64];

  int tid = threadIdx.x, w = tid >> 6, lane = tid & 63;
  int lr = lane & 15, lg = lane >> 4;
  int wm = w / WN, wn = w % WN;

  // bijective XCD swizzle (grid % 8 == 0)
  int q = (int)gridDim.x >> 3;
  int bid = (int)blockIdx.x;
  int swz = (bid & 7) * q + (bid >> 3);
  int mBlk = (swz / ntn) * BM, nBlk = (swz % ntn) * BN;

  v4f acc[MF][NF];
#pragma unroll
  for (int i = 0; i < MF; ++i)
#pragma unroll
    for (int j = 0; j < NF; ++j) acc[i][j] = (v4f){0.f, 0.f, 0.f, 0.f};

  // staging: call c covers rows c*64..+63; lane t -> row c*64 + (t>>3),
  // LDS slot t&7 (linear), GLOBAL slot (t&7) ^ (row&7)  [inverse swizzle]
  int tr = tid >> 3;                    // row within call (0..63)
  int sg = (tid & 7) ^ (tr & 7);        // swizzled global slot
  const UST* AbL = A + (size_t)(mBlk + tr) * K + sg * 8;
  const UST* BbL = Bt + (size_t)(nBlk + tr) * K + sg * 8;
  int ldsW = w * 512;                   // wave-uniform offset within a call block

  auto stageA = [&](int bf, int kt) {
#pragma unroll
    for (int c = 0; c < CA; ++c)
      gl_lds16(AbL + (size_t)(c * 64) * K + kt * 64,
               &lds[bf * BM * 64 + c * 4096 + ldsW]);
  };
  auto stageB = [&](int bf, int kt) {
#pragma unroll
    for (int c = 0; c < CB; ++c)
      gl_lds16(BbL + (size_t)(c * 64) * K + kt * 64,
               &lds[AE + bf * BN * 64 + c * 4096 + ldsW]);
  };
  // frag reads: row-XOR on the 16B slot (row&7 == lr&7 since bases are mult of 8)
  auto ldA = [&](int bf, int s, int f) -> v8bf {
    int row = wm * WMR + f * 16 + lr;
    return *(const v8bf*)&lds[(bf * BM + row) * 64 + (((s * 4 + lg) ^ (lr & 7)) * 8)];
  };
  auto ldB = [&](int bf, int s, int nf) -> v8bf {
    int row = wn * WNR + nf * 16 + lr;
    return *(const v8bf*)&lds[AE + (bf * BN + row) * 64 + (((s * 4 + lg) ^ (lr & 7)) * 8)];
  };

  int NT = K >> 6;  // K-tiles of 64
  stageA(0, 0); stageB(0, 0);   // prologue: tile 0 in flight

  for (int kt = 0; kt < NT; ++kt) {
    int bf = kt & 1, nb = bf ^ 1;
    if (kt + 1 < NT) {
      stageA(nb, kt + 1); stageB(nb, kt + 1);   // prefetch next tile
      wait_vm<NKEEP>();                          // current tile's calls done
    } else {
      wait_vm<0>();
    }
    __syncthreads();   // tile bf visible to all waves
#pragma unroll
    for (int s = 0; s < 2; ++s) {
      v8bf afr[MF], bfr[NF];
#pragma unroll
      for (int nf = 0; nf < NF; ++nf) bfr[nf] = ldB(bf, s, nf);
#pragma unroll
      for (int f = 0; f < MF; ++f) afr[f] = ldA(bf, s, f);
      __builtin_amdgcn_s_setprio(1);
#pragma unroll
      for (int f = 0; f < MF; ++f)
#pragma unroll
        for (int nf = 0; nf < NF; ++nf)
          acc[f][nf] = __builtin_amdgcn_mfma_f32_16x16x32_bf16(
              afr[f], bfr[nf], acc[f][nf], 0, 0, 0);
      __builtin_amdgcn_s_setprio(0);
    }
    __syncthreads();   // all reads of bf done -> next iter may stage into bf
  }

  // epilogue: C/D layout col = lane&15, row = 4*(lane>>4)+reg
  int row0 = mBlk + wm * WMR + lg * 4;
  int col0 = nBlk + wn * WNR + lr;
#pragma unroll
  for (int fm = 0; fm < MF; ++fm)
#pragma unroll
    for (int nf = 0; nf < NF; ++nf)
#pragma unroll
      for (int r = 0; r < 4; ++r) {
        int row = row0 + fm * 16 + r;
        int col = col0 + nf * 16;
        if constexpr (EPI == 0) {
          ((UST*)Cv)[(size_t)row * N + col] = f2b(acc[fm][nf][r]);
        } else {
          ((float*)Cv)[(size_t)row * N + col] = acc[fm][nf][r] + bias[col];
        }
      }
}

// ---------------- RoPE on q,k (q pre-scaled by 1/sqrt(64)) ----------------
__global__ __launch_bounds__(256) void k_rope(const UST* __restrict__ qkv,
                                              const float* __restrict__ cosT,
                                              const float* __restrict__ sinT,
                                              UST* __restrict__ qh,
                                              UST* __restrict__ kh) {
  int idx = blockIdx.x * 256 + threadIdx.x;
  int d = idx & 31;
  int hh = (idx >> 5) % 40;
  int row = idx / 1280;
  int l = row & 2047, b = row >> 11;
  int col = (hh < 32) ? hh * 64 : 2048 + (hh - 32) * 64;
  float t1 = b2f(qkv[(size_t)row * 3072 + col + d]);
  float t2 = b2f(qkv[(size_t)row * 3072 + col + d + 32]);
  float c = cosT[l * 64 + d], s = sinT[l * 64 + d];
  float o1 = t1 * c - t2 * s;
  float o2 = t2 * c + t1 * s;
  if (hh < 32) {
    size_t base = (((size_t)b * 32 + hh) * 2048 + l) * 64 + d;
    qh[base] = f2b(o1 * 0.125f);
    qh[base + 32] = f2b(o2 * 0.125f);
  } else {
    size_t base = (((size_t)b * 8 + (hh - 32)) * 2048 + l) * 64 + d;
    kh[base] = f2b(o1);
    kh[base + 32] = f2b(o2);
  }
}

// ---------------- V transpose: qkv v-slice -> vt [B][8][64][L] ----------------
__global__ __launch_bounds__(256) void k_vtrans(const UST* __restrict__ qkv,
                                                UST* __restrict__ vt) {
  __shared__ __align__(16) UST tl[64][72];
  int lt = blockIdx.x, bg = blockIdx.y;
  int b = bg >> 3, g = bg & 7;
  int t = threadIdx.x;
  int li = t >> 2, d0 = (t & 3) * 16;
  const UST* src = qkv + (size_t)(b * 2048 + lt * 64 + li) * 3072 + 2560 + g * 64 + d0;
  *(uint4*)&tl[li][d0] = *(const uint4*)src;
  *(uint4*)&tl[li][d0 + 8] = *(const uint4*)(src + 8);
  __syncthreads();
  int d = t >> 2, l0 = (t & 3) * 16;
  union { UST u[8]; uint4 v; } r0, r1;
#pragma unroll
  for (int e = 0; e < 8; ++e) r0.u[e] = tl[l0 + e][d];
#pragma unroll
  for (int e = 0; e < 8; ++e) r1.u[e] = tl[l0 + 8 + e][d];
  UST* dstp = vt + (size_t)((b * 8 + g) * 64 + d) * 2048 + (size_t)lt * 64 + l0;
  *(uint4*)dstp = r0.v;
  *(uint4*)(dstp + 8) = r1.v;
}

// ---------------- causal flash attention: balanced pairs (round-5 proven) ----------------
// grid (8, 32, 2), 8 waves x 16 q-rows. Block handles q-tiles bx and 15-bx
// (QBLK=128 each) -> exactly 17 KV-iterations per block; 512 blocks = 2/CU
// all co-resident. Swapped S^T = mfma(K, Q): lane holds q-row lr,
// kpos = kt*16 + 4*lg + r.
__global__ __launch_bounds__(512, 4) void k_attn(const UST* __restrict__ qh,
                                                 const UST* __restrict__ kh,
                                                 const UST* __restrict__ vt,
                                                 UST* __restrict__ outp) {
  __shared__ __align__(16) UST k_s[128 * 72];       // K tile [kpos][64], pad->72
  __shared__ __align__(16) UST v_s[64 * 136];       // V^T tile [d][128], pad->136
  __shared__ __align__(16) UST p_s[8][16 * 136];    // per-wave P [16 q][128 k]
  int bx = blockIdx.x, h = blockIdx.y, b = blockIdx.z;
  int g = h >> 2;
  int tid = threadIdx.x, w = tid >> 6, lane = tid & 63;
  int lr = lane & 15, lg = lane >> 4;

  int ksr = tid >> 2, ksc = (tid & 3) * 16;
  int vsr = tid >> 3, vsc = (tid & 7) * 16;
  const UST* kbase = kh + ((size_t)(b * 8 + g) * 2048 + ksr) * 64 + ksc;
  const UST* vbase = vt + ((size_t)(b * 8 + g) * 64 + vsr) * 2048 + vsc;
  UST* kdst = &k_s[ksr * 72 + ksc];
  UST* vdst = &v_s[vsr * 136 + vsc];

  for (int half = 0; half < 2; ++half) {
    int qt = half ? (15 - bx) : bx;
    int qbase = qt * 128 + w * 16;

    const UST* qp = qh + ((size_t)(b * 32 + h) * 2048 + qbase + lr) * 64 + lg * 8;
    v8bf qf0 = *(const v8bf*)qp;
    v8bf qf1 = *(const v8bf*)(qp + 32);

    float m = -1e30f, ls = 0.f;
    v4f o[4];
#pragma unroll
    for (int dt = 0; dt < 4; ++dt) o[dt] = (v4f){0.f, 0.f, 0.f, 0.f};

    __syncthreads();  // prior half's tile reads complete
    uint4 pk0 = *(const uint4*)kbase, pk1 = *(const uint4*)(kbase + 8);
    uint4 pv0 = *(const uint4*)vbase, pv1 = *(const uint4*)(vbase + 8);
    *(uint4*)kdst = pk0; *(uint4*)(kdst + 8) = pk1;
    *(uint4*)vdst = pv0; *(uint4*)(vdst + 8) = pv1;

    for (int j = 0; j <= qt; ++j) {
      __syncthreads();  // staged tile visible
      bool pref = (j < qt);
      if (pref) {  // register-prefetch next tile; hides under compute
        const UST* kg = kbase + (size_t)(j + 1) * 8192;
        const UST* vg = vbase + (j + 1) * 128;
        pk0 = *(const uint4*)kg; pk1 = *(const uint4*)(kg + 8);
        pv0 = *(const uint4*)vg; pv1 = *(const uint4*)(vg + 8);
      }

      // S^T = K * Q^T : 16 MFMAs
      v4f st[8];
      __builtin_amdgcn_s_setprio(1);
#pragma unroll
      for (int kt = 0; kt < 8; ++kt) {
        const UST* kr = &k_s[(kt * 16 + lr) * 72 + lg * 8];
        v8bf kf0 = *(const v8bf*)kr;
        v8bf kf1 = *(const v8bf*)(kr + 32);
        v4f z = (v4f){0.f, 0.f, 0.f, 0.f};
        z = __builtin_amdgcn_mfma_f32_16x16x32_bf16(kf0, qf0, z, 0, 0, 0);
        z = __builtin_amdgcn_mfma_f32_16x16x32_bf16(kf1, qf1, z, 0, 0, 0);
        st[kt] = z;
      }
      __builtin_amdgcn_s_setprio(0);
      if (j == qt) {  // diagonal: causal mask
        int qg = qbase + lr;
#pragma unroll
        for (int kt = 0; kt < 8; ++kt)
#pragma unroll
          for (int r = 0; r < 4; ++r) {
            int kg2 = j * 128 + kt * 16 + 4 * lg + r;
            if (kg2 > qg) st[kt][r] = -1e30f;
          }
      }

      float t0 = fmaxf(fmaxf(st[0][0], st[0][1]), fmaxf(st[0][2], st[0][3]));
      float t1 = fmaxf(fmaxf(st[1][0], st[1][1]), fmaxf(st[1][2], st[1][3]));
      float t2 = fmaxf(fmaxf(st[2][0], st[2][1]), fmaxf(st[2][2], st[2][3]));
      float t3 = fmaxf(fmaxf(st[3][0], st[3][1]), fmaxf(st[3][2], st[3][3]));
      float t4 = fmaxf(fmaxf(st[4][0], st[4][1]), fmaxf(st[4][2], st[4][3]));
      float t5 = fmaxf(fmaxf(st[5][0], st[5][1]), fmaxf(st[5][2], st[5][3]));
      float t6 = fmaxf(fmaxf(st[6][0], st[6][1]), fmaxf(st[6][2], st[6][3]));
      float t7 = fmaxf(fmaxf(st[7][0], st[7][1]), fmaxf(st[7][2], st[7][3]));
      float mx = fmaxf(fmaxf(fmaxf(t0, t1), fmaxf(t2, t3)),
                       fmaxf(fmaxf(t4, t5), fmaxf(t6, t7)));
      mx = fmaxf(mx, __shfl_xor(mx, 16));
      mx = fmaxf(mx, __shfl_xor(mx, 32));

      if (!__all(mx <= m + 8.f)) {   // defer-max (T13)
        float mn = fmaxf(m, mx);
        float al = __expf(m - mn);
        m = mn;
        ls *= al;
#pragma unroll
        for (int r = 0; r < 4; ++r) {
          float ar = __shfl(al, 4 * lg + r);
          o[0][r] *= ar; o[1][r] *= ar; o[2][r] *= ar; o[3][r] *= ar;
        }
      }

      constexpr float LOG2E = 1.44269504f;
      float mlog = m * LOG2E;
      float rs = 0.f;
      UST* pw = &p_s[w][lr * 136 + 4 * lg];
#pragma unroll
      for (int kt = 0; kt < 8; ++kt) {
        float p0 = fexp2(__builtin_fmaf(st[kt][0], LOG2E, -mlog));
        float p1 = fexp2(__builtin_fmaf(st[kt][1], LOG2E, -mlog));
        float p2 = fexp2(__builtin_fmaf(st[kt][2], LOG2E, -mlog));
        float p3 = fexp2(__builtin_fmaf(st[kt][3], LOG2E, -mlog));
        rs += (p0 + p1) + (p2 + p3);
        uint2 q2;
        q2.x = cvtpk(p0, p1);
        q2.y = cvtpk(p2, p3);
        *(uint2*)(pw + kt * 16) = q2;
      }
      rs += __shfl_xor(rs, 16);
      rs += __shfl_xor(rs, 32);
      ls += rs;

      // PV: 16 MFMAs
      __builtin_amdgcn_s_setprio(1);
#pragma unroll
      for (int kk = 0; kk < 4; ++kk) {
        v8bf pa = *(const v8bf*)&p_s[w][lr * 136 + kk * 32 + lg * 8];
#pragma unroll
        for (int dt = 0; dt < 4; ++dt) {
          v8bf vb = *(const v8bf*)&v_s[(dt * 16 + lr) * 136 + kk * 32 + lg * 8];
          o[dt] = __builtin_amdgcn_mfma_f32_16x16x32_bf16(pa, vb, o[dt], 0, 0, 0);
        }
      }
      __builtin_amdgcn_s_setprio(0);

      __syncthreads();  // tile reads done
      if (pref) {
        *(uint4*)kdst = pk0; *(uint4*)(kdst + 8) = pk1;
        *(uint4*)vdst = pv0; *(uint4*)(vdst + 8) = pv1;
      }
    }

    // epilogue: normalize and store O as [B*L][H*64] bf16
    float iv = 1.f / ls;
#pragma unroll
    for (int r = 0; r < 4; ++r) {
      float ivr = __shfl(iv, 4 * lg + r);
      size_t rowb = ((size_t)b * 2048 + qbase + 4 * lg + r) * 2048 + h * 64 + lr;
#pragma unroll
      for (int dt = 0; dt < 4; ++dt)
        outp[rowb + dt * 16] = f2b(o[dt][r] * ivr);
    }
  }
}

// ---------------- launch ----------------
extern "C" void kernel_launch(void* const* d_in, const int* in_sizes, int n_in,
                              void* d_out, int out_size, void* d_ws, size_t ws_size,
                              hipStream_t stream) {
  const float* x    = (const float*)d_in[0];
  const float* cosT = (const float*)d_in[2];
  const float* sinT = (const float*)d_in[3];
  const float* Wq   = (const float*)d_in[4];
  const float* Wk   = (const float*)d_in[5];
  const float* Wv   = (const float*)d_in[6];
  const float* Wo   = (const float*)d_in[7];
  const float* bo   = (const float*)d_in[8];
  float* out = (float*)d_out;

  char* ws = (char*)d_ws;
  UST* xb   = (UST*)(ws);                       // 16777216 B
  UST* wcat = (UST*)(ws + 16777216);            // 12582912 B
  UST* wot  = (UST*)(ws + 29360128);            //  8388608 B
  UST* qkv  = (UST*)(ws + 37748736);            // 25165824 B
  UST* qhp  = (UST*)(ws + 62914560);            // 16777216 B
  UST* khp  = (UST*)(ws + 79691776);            //  4194304 B
  UST* vtp  = (UST*)(ws + 83886080);            //  4194304 B
  UST* attn_o = xb;  // xb dead after QKV GEMM

  k_cast<<<4096, 256, 0, stream>>>(x, xb);
  k_castT<<<dim3(64, 64), dim3(32, 8), 0, stream>>>(Wq, wcat, 2048, 2048);
  k_castT<<<dim3(16, 64), dim3(32, 8), 0, stream>>>(Wk, wcat + (size_t)2048 * 2048, 512, 2048);
  k_castT<<<dim3(16, 64), dim3(32, 8), 0, stream>>>(Wv, wcat + (size_t)2560 * 2048, 512, 2048);
  k_castT<<<dim3(64, 64), dim3(32, 8), 0, stream>>>(Wo, wot, 2048, 2048);

  // QKV: M=4096, N=3072, K=2048; 256x192 tiles -> 16x16 = 256 blocks (perfect fill)
  k_gemm2<256, 192, 2, 4, 0><<<256, 512, 0, stream>>>(xb, wcat, qkv, nullptr,
                                                      4096, 3072, 2048, 16);
  k_rope<<<20480, 256, 0, stream>>>(qkv, cosT, sinT, qhp, khp);
  k_vtrans<<<dim3(32, 16), 256, 0, stream>>>(qkv, vtp);
  k_attn<<<dim3(8, 32, 2), 512, 0, stream>>>(qhp, khp, vtp, attn_o);
  // out: M=4096, N=2048, K=2048; 256x128 tiles -> 16x16 = 256 blocks (full fill)
  k_gemm2<256, 128, 4, 2, 1><<<256, 512, 0, stream>>>(attn_o, wot, out, bo,
                                                      4096, 2048, 2048, 16);
}